// Round 13
// baseline (283.364 us; speedup 1.0000x reference)
//
#include <hip/hip_runtime.h>

#define NN 50000
#define NE 1600000
#define FIN 128
#define FOUT 64
#define ALPHA 0.2f

#define RANGE 64           // destination nodes per bucket
#define NBK 782            // ceil(NN / RANGE) buckets
#define CAP 4096           // LDS pairs capacity (uniform mean 2046, sigma~45)
#define EPB 2048           // edges per block in pass A / cnt
#define NBLK 782           // ceil(NE / EPB)

typedef float v2f __attribute__((ext_vector_type(2)));

__device__ inline int ldi(const void* p, size_t i, int isi64) {
    int v = isi64 ? (int)((const long long*)p)[i] : ((const int*)p)[i];
    return v < 0 ? 0 : (v >= NN ? NN - 1 : v);  // clamp: no data-dependent OOB
}

// f32 -> bf16 round-to-nearest-even
__device__ inline unsigned short f2bf(float x) {
    unsigned u = __float_as_uint(x);
    return (unsigned short)((u + 0x7FFFu + ((u >> 16) & 1u)) >> 16);
}

// unpack uint (2 bf16) -> v2f {even, odd}
__device__ inline v2f bfu2(unsigned u) {
    v2f r;
    r.x = __uint_as_float(u << 16);
    r.y = __uint_as_float(u & 0xFFFF0000u);
    return r;
}

// ---------- K0: fused {int-width sniffer | u = W @ {a1l,a1r,a2l,a2r}} ----------
__global__ __launch_bounds__(256) void k_su(const int* __restrict__ edge32, int* __restrict__ iflag,
                                            const float* __restrict__ W, const float* __restrict__ a1,
                                            const float* __restrict__ a2, float* __restrict__ u) {
    if (blockIdx.x == 0) {
        __shared__ int zodd;
        if (threadIdx.x == 0) zodd = 0;
        __syncthreads();
        int z = 0;
        for (int i = threadIdx.x; i < 2048; i += 256)
            if (edge32[2 * i + 1] == 0) z++;    // int64 high words are always 0
        atomicAdd(&zodd, z);
        __syncthreads();
        if (threadIdx.x == 0) *iflag = (zodd > 2000) ? 1 : 0;
    } else {
        int k = threadIdx.x;  // 0..127 active
        if (k < FIN) {
            float u1 = 0.f, u2 = 0.f, u3 = 0.f, u4 = 0.f;
            for (int j = 0; j < FOUT; j++) {
                float w = W[k * FOUT + j];
                u1 += w * a1[j];
                u2 += w * a1[FOUT + j];
                u3 += w * a2[j];
                u4 += w * a2[FOUT + j];
            }
            u[k] = u1; u[128 + k] = u2; u[256 + k] = u3; u[384 + k] = u4;
        }
    }
}

// ---------- K1: h = input @ W  (N x 64, stored bf16 — consumed only by k_aggB) ----------
__global__ __launch_bounds__(256) void k_gemm(const float* __restrict__ X,
                                              const float* __restrict__ W,
                                              unsigned short* __restrict__ h) {
    __shared__ float wlds[FIN * FOUT];      // 32 KB
    __shared__ float xlds[4][4][FIN];       // 8 KB
    int tid = threadIdx.x;
    for (int i = tid; i < FIN * FOUT; i += 256) wlds[i] = W[i];
    int wave = tid >> 6, lane = tid & 63;
    int base = blockIdx.x * 16 + wave * 4;  // 3125*16 = 50000 exact
    for (int n0 = 0; n0 < 4; n0++) {
        float2 b = ((const float2*)(X + (size_t)(base + n0) * FIN))[lane];
        xlds[wave][n0][2 * lane] = b.x;
        xlds[wave][n0][2 * lane + 1] = b.y;
    }
    __syncthreads();
    float a0 = 0.f, a1v = 0.f, a2v = 0.f, a3 = 0.f;
    for (int k = 0; k < FIN; k++) {
        float w = wlds[k * FOUT + lane];
        a0  += xlds[wave][0][k] * w;
        a1v += xlds[wave][1][k] * w;
        a2v += xlds[wave][2][k] * w;
        a3  += xlds[wave][3][k] * w;
    }
    h[(size_t)(base + 0) * FOUT + lane] = f2bf(a0);
    h[(size_t)(base + 1) * FOUT + lane] = f2bf(a1v);
    h[(size_t)(base + 2) * FOUT + lane] = f2bf(a2v);
    h[(size_t)(base + 3) * FOUT + lane] = f2bf(a3);
}

// ---------- K1b: fused {per-node score scalars | per-block bucket counts} ----------
__global__ __launch_bounds__(256) void k_svec_cnt(const float* __restrict__ input,
                                                  const float* __restrict__ p_h,
                                                  const float* __restrict__ new_h,
                                                  const float* __restrict__ u,
                                                  float* __restrict__ s1, float* __restrict__ s2,
                                                  float* __restrict__ sc /* float2 as float* */,
                                                  float* __restrict__ s4,
                                                  const void* __restrict__ edge,
                                                  const int* __restrict__ iflag,
                                                  int* __restrict__ cntm) {
    __shared__ int hist[NBK];
    int tid = threadIdx.x;
    if (blockIdx.x < 12500) {
        int lane = tid & 63;
        int v = blockIdx.x * 4 + (tid >> 6);
        size_t row = (size_t)v * FIN;
        float2 bi = ((const float2*)(input + row))[lane];
        float2 bp = ((const float2*)(p_h   + row))[lane];
        float2 bn = ((const float2*)(new_h + row))[lane];
        float p1 = bi.x * u[2 * lane]       + bi.y * u[2 * lane + 1];
        float p2 = bp.x * u[128 + 2 * lane] + bp.y * u[128 + 2 * lane + 1];
        float p3 = bn.x * u[256 + 2 * lane] + bn.y * u[256 + 2 * lane + 1];
        float p4 = bi.x * u[384 + 2 * lane] + bi.y * u[384 + 2 * lane + 1];
#pragma unroll
        for (int off = 32; off > 0; off >>= 1) {
            p1 += __shfl_down(p1, off, 64);
            p2 += __shfl_down(p2, off, 64);
            p3 += __shfl_down(p3, off, 64);
            p4 += __shfl_down(p4, off, 64);
        }
        if (lane == 0) { s1[v] = p1; s2[v] = p2; sc[2 * v] = p3; s4[v] = p4; }
    } else {
        int cb = blockIdx.x - 12500;                  // 0..781
        for (int t = tid; t < NBK; t += 256) hist[t] = 0;
        __syncthreads();
        int i64 = *iflag;
        int base = cb * EPB;
        int b0[8]; bool act[8];
#pragma unroll
        for (int k = 0; k < 8; k++) {                 // phase 1: 8 independent loads
            int e = base + k * 256 + tid;
            act[k] = e < NE;
            b0[k] = ldi(edge, act[k] ? e : NE - 1, i64) >> 6;
        }
#pragma unroll
        for (int k = 0; k < 8; k++)                   // phase 2: 8 LDS atomics
            if (act[k]) atomicAdd(&hist[b0[k]], 1);
        __syncthreads();
        for (int t = tid; t < NBK; t += 256)
            cntm[(size_t)cb * NBK + t] = hist[t];     // plain coalesced row store
    }
}

// ---------- K2: col score + exp + segment max ----------
__global__ void k_colscore(const float* __restrict__ s1, const float* __restrict__ s2,
                           const void* __restrict__ edge_col, const void* __restrict__ row_i,
                           const int* __restrict__ iflag,
                           float* __restrict__ ec, unsigned int* __restrict__ m) {
    int i = blockIdx.x * 256 + threadIdx.x;
    if (i >= NN) return;
    int i64 = *iflag;
    float cs = s1[ldi(edge_col, i, i64)] + s2[i];
    float l = cs > 0.f ? cs : ALPHA * cs;
    float e = expf(-l);                // > 0 always
    ec[i] = e;
    atomicMax(&m[ldi(row_i, i, i64)], __float_as_uint(e));  // init 0, e>0 -> valid
}

// ---------- K3: ex = exp(ec - m) in place; segment sum ----------
__global__ void k_expsum(float* __restrict__ ec, const unsigned int* __restrict__ m,
                         const void* __restrict__ row_i, const int* __restrict__ iflag,
                         float* __restrict__ ssum) {
    int i = blockIdx.x * 256 + threadIdx.x;
    if (i >= NN) return;
    int r = ldi(row_i, i, *iflag);
    float e = expf(ec[i] - __uint_as_float(m[r]));
    ec[i] = e;
    atomicAdd(&ssum[r], e);
}

// ---------- K4: normalize -> sc[i].y = ecs ----------
__global__ void k_norm(const float* __restrict__ ex, const float* __restrict__ ssum,
                       const void* __restrict__ row_i, const int* __restrict__ iflag,
                       float* __restrict__ sc /* float2 as float* */) {
    int i = blockIdx.x * 256 + threadIdx.x;
    if (i >= NN) return;
    sc[2 * i + 1] = ex[i] / (ssum[ldi(row_i, i, *iflag)] + 1e-16f);
}

// ---------- K5b1: per-bucket column scan over 782 blocks -> colpre, bcnt ----------
__global__ __launch_bounds__(1024) void k_colscan(const int* __restrict__ cntm,
                                                  int* __restrict__ colpre,
                                                  int* __restrict__ bcnt) {
    __shared__ int s[1024];
    int b = blockIdx.x, tid = threadIdx.x;
    int x = (tid < NBLK) ? cntm[(size_t)tid * NBK + b] : 0;
    s[tid] = x;
    __syncthreads();
    for (int off = 1; off < 1024; off <<= 1) {
        int t = (tid >= off) ? s[tid - off] : 0;
        __syncthreads();
        s[tid] += t;
        __syncthreads();
    }
    if (tid < NBLK) colpre[(size_t)tid * NBK + b] = s[tid] - x;  // exclusive within column
    if (tid == 1023) bcnt[b] = s[1023];                          // column total
}

// ---------- K5b2: scan 782 bucket totals -> bstart; sentinel ----------
__global__ __launch_bounds__(1024) void k_bscan(const int* __restrict__ bcnt,
                                                int* __restrict__ bstart) {
    __shared__ int s[1024];
    int tid = threadIdx.x;
    int x = (tid < NBK) ? bcnt[tid] : 0;
    s[tid] = x;
    __syncthreads();
    for (int off = 1; off < 1024; off <<= 1) {
        int t = (tid >= off) ? s[tid - off] : 0;
        __syncthreads();
        s[tid] += t;
        __syncthreads();
    }
    if (tid < NBK) bstart[tid] = s[tid] - x;
    if (tid == 0) bstart[NBK] = NE;
}

// ---------- K5c pass A: explicit-MLP phase-split; single barrier ----------
__global__ __launch_bounds__(512) void k_edgeA(const float2* __restrict__ sc, const float* __restrict__ s4,
                                               const void* __restrict__ edge, const void* __restrict__ row_resort,
                                               const int* __restrict__ iflag,
                                               const int* __restrict__ bstart, const int* __restrict__ colpre,
                                               uint2* __restrict__ tmp,
                                               float* __restrict__ edge_e /* = out2 */) {
    __shared__ int hist[NBK];
    __shared__ int bbase[NBK];
    int tid = threadIdx.x;
    for (int t = tid; t < NBK; t += 512) {
        hist[t] = 0;
        bbase[t] = bstart[t] + colpre[(size_t)blockIdx.x * NBK + t];  // prefetch, hist-independent
    }
    __syncthreads();
    int i64 = *iflag;
    int base = blockIdx.x * EPB;
    int e0[4], e1[4], rr[4]; bool act[4];
#pragma unroll
    for (int k = 0; k < 4; k++) {                     // phase 1: 12 independent index loads
        int e = base + k * 512 + tid;
        act[k] = e < NE;
        size_t ec = act[k] ? (size_t)e : (size_t)(NE - 1);  // clamped: loads always legal
        e0[k] = ldi(edge, ec, i64);
        e1[k] = ldi(edge, (size_t)NE + ec, i64);
        rr[k] = ldi(row_resort, ec, i64);
    }
    float2 c[4]; float s4v[4];
#pragma unroll
    for (int k = 0; k < 4; k++) {                     // phase 2: 8 independent gathers
        c[k] = sc[rr[k]];
        s4v[k] = s4[e1[k]];
    }
    unsigned key[4]; float val[4]; int rk[4], bk[4];
#pragma unroll
    for (int k = 0; k < 4; k++) {                     // phase 3: compute + rank + numerator
        float rsv = c[k].x + s4v[k];
        float l = rsv > 0.f ? rsv : ALPHA * rsv;
        float ee = expf(-l) * c[k].y;
        if (act[k]) edge_e[base + k * 512 + tid] = ee;
        key[k] = (unsigned)e0[k] | ((unsigned)e1[k] << 16);   // both < 65536
        val[k] = ee;
        bk[k] = e0[k] >> 6;                           // bucket = e0 / RANGE
        rk[k] = act[k] ? atomicAdd(&hist[bk[k]], 1) : 0;      // rank within (block,bucket)
    }
#pragma unroll
    for (int k = 0; k < 4; k++)                       // scatter: no barrier needed
        if (act[k])
            tmp[bbase[bk[k]] + rk[k]] = make_uint2(key[k], __float_as_uint(val[k]));
}

// ---------- K6: fused {fine-sort into LDS | gather-aggregate} per 64-node bucket ----------
// One block per bucket (782 ~ 3/CU). Pass 1: count 64 node pops; scan. Pass 2:
// scatter the bucket's ~2046 records into a 32 KB LDS pairs array (overflow >CAP
// spills to the global buffer — never triggers at uniform load). Agg: 8 waves x
// 8 nodes, 8-slot x 8-feat layout; pairs hop is now LDS (~30 cy) instead of L2
// (~200 cy) on the critical chain feeding the h-gather address.
__global__ __launch_bounds__(512) void k_aggB(const unsigned short* __restrict__ h,
                                              const uint2* __restrict__ tmp,
                                              const int* __restrict__ bstart,
                                              uint2* __restrict__ spill,
                                              float* __restrict__ ersum,
                                              float* __restrict__ out0) {
    __shared__ uint2 lp[CAP];                         // 32 KB
    __shared__ int cnt[RANGE];
    __shared__ int bs[RANGE];
    __shared__ int cur[RANGE];
    int tid = threadIdx.x;
    int b = blockIdx.x;
    int v0 = b * RANGE;
    if (tid < RANGE) cnt[tid] = 0;
    __syncthreads();
    int lo = bstart[b], hi = bstart[b + 1];
    int sz = hi - lo;
    for (int i = lo + tid; i < hi; i += 512)          // pass 1: node populations
        atomicAdd(&cnt[tmp[i].x & (RANGE - 1)], 1);
    __syncthreads();
    if (tid < RANGE) bs[tid] = cnt[tid];
    __syncthreads();
    for (int off = 1; off < RANGE; off <<= 1) {       // scan 64
        int t = 0;
        if (tid < RANGE && tid >= off) t = bs[tid - off];
        __syncthreads();
        if (tid < RANGE) bs[tid] += t;
        __syncthreads();
    }
    if (tid < RANGE) {
        int g = bs[tid] - cnt[tid];                   // exclusive, bucket-relative
        bs[tid] = g;
        cur[tid] = g;
    }
    __syncthreads();
    bool inl = sz <= CAP;
    if (inl) {
        for (int i = lo + tid; i < hi; i += 512) {    // pass 2: grouped scatter -> LDS
            uint2 r = tmp[i];
            int pos = atomicAdd(&cur[r.x & (RANGE - 1)], 1);
            lp[pos] = make_uint2(r.x >> 16, r.y);
        }
    } else {
        for (int i = lo + tid; i < hi; i += 512) {    // skew fallback -> global
            uint2 r = tmp[i];
            int pos = atomicAdd(&cur[r.x & (RANGE - 1)], 1);
            spill[lo + pos] = make_uint2(r.x >> 16, r.y);
        }
    }
    __syncthreads();
    const uint2* src = inl ? (const uint2*)lp : (spill + lo);
    int lane = tid & 63, wid = tid >> 6;
    int q = lane >> 3, fq = lane & 7;
    for (int nn = 0; nn < 8; nn++) {                  // 8 nodes per wave
        int n = wid * 8 + nn;
        int a = bs[n];
        int bnd = a + cnt[n];
        v2f a01 = {0.f, 0.f}, a23 = {0.f, 0.f}, a45 = {0.f, 0.f}, a67 = {0.f, 0.f};
        float rs = 0.f;
        int bfull = a + ((bnd - a) & ~15);
        int j = a;
        for (; j < bfull; j += 16) {                  // no bounds checks
            uint2 pA = src[j + q];
            uint2 pB = src[j + 8 + q];
            float eeA = __uint_as_float(pA.y), eeB = __uint_as_float(pB.y);
            uint4 hA = *(const uint4*)(h + (((size_t)pA.x) << 6) + 8 * fq);
            uint4 hB = *(const uint4*)(h + (((size_t)pB.x) << 6) + 8 * fq);
            v2f eA = {eeA, eeA}, eB = {eeB, eeB};
            a01 += eA * bfu2(hA.x);
            a23 += eA * bfu2(hA.y);
            a45 += eA * bfu2(hA.z);
            a67 += eA * bfu2(hA.w);
            a01 += eB * bfu2(hB.x);
            a23 += eB * bfu2(hB.y);
            a45 += eB * bfu2(hB.z);
            a67 += eB * bfu2(hB.w);
            rs += eeA + eeB;
        }
        if (j < bnd) {                                // guarded tail, single pass
            int iA = j + q, iB = j + 8 + q;
            bool vA = iA < bnd, vB = iB < bnd;
            uint2 pA = src[vA ? iA : a];
            uint2 pB = src[vB ? iB : a];
            float eeA = vA ? __uint_as_float(pA.y) : 0.f;
            float eeB = vB ? __uint_as_float(pB.y) : 0.f;
            uint4 hA = *(const uint4*)(h + (((size_t)pA.x) << 6) + 8 * fq);
            uint4 hB = *(const uint4*)(h + (((size_t)pB.x) << 6) + 8 * fq);
            v2f eA = {eeA, eeA}, eB = {eeB, eeB};
            a01 += eA * bfu2(hA.x);
            a23 += eA * bfu2(hA.y);
            a45 += eA * bfu2(hA.z);
            a67 += eA * bfu2(hA.w);
            a01 += eB * bfu2(hB.x);
            a23 += eB * bfu2(hB.y);
            a45 += eB * bfu2(hB.z);
            a67 += eB * bfu2(hB.w);
            rs += eeA + eeB;
        }
#pragma unroll
        for (int off = 8; off <= 32; off <<= 1) {     // reduce across edge slots (q bits)
            v2f t01, t23, t45, t67;
            t01.x = __shfl_xor(a01.x, off, 64); t01.y = __shfl_xor(a01.y, off, 64);
            t23.x = __shfl_xor(a23.x, off, 64); t23.y = __shfl_xor(a23.y, off, 64);
            t45.x = __shfl_xor(a45.x, off, 64); t45.y = __shfl_xor(a45.y, off, 64);
            t67.x = __shfl_xor(a67.x, off, 64); t67.y = __shfl_xor(a67.y, off, 64);
            a01 += t01; a23 += t23; a45 += t45; a67 += t67;
            rs  += __shfl_xor(rs, off, 64);
        }
        // one result per lane: feature 8*fq + q (pair q>>1, component q&1)
        v2f ap = (q >> 1) == 0 ? a01 : (q >> 1) == 1 ? a23 : (q >> 1) == 2 ? a45 : a67;
        float av = (q & 1) ? ap.y : ap.x;
        rs += (rs == 0.f) ? 1.f : 0.f;                // empty-segment fixup
        float ev = av / rs;
        ev = ev > 0.f ? ev : expm1f(ev);
        int v = v0 + n;
        if (v < NN) {
            out0[(size_t)v * FOUT + 8 * fq + q] = ev; // permuted within 256B row
            if (lane == 0) ersum[v] = rs;
        }
    }
}

// ---------- K7: out1 = float(edge) AND out2 /= ersum[e0] (fused, runs LAST) ----------
__global__ __launch_bounds__(256) void k_final(const void* __restrict__ edge, const int* __restrict__ iflag,
                                               const float* __restrict__ ersum,
                                               float* __restrict__ out2, float* __restrict__ out1) {
    int i = blockIdx.x * 256 + threadIdx.x;           // 12500*256 = 2*NE exact
    int i64 = *iflag;
    int v = i64 ? (int)((const long long*)edge)[i] : ((const int*)edge)[i];
    out1[i] = (float)v;
    if (i < NE) {                                     // edge[0..NE) is row 0 = e0
        int e0 = v < 0 ? 0 : (v >= NN ? NN - 1 : v);
        out2[i] = out2[i] / ersum[e0];
    }
}

extern "C" void kernel_launch(void* const* d_in, const int* in_sizes, int n_in,
                              void* d_out, int out_size, void* d_ws, size_t ws_size,
                              hipStream_t stream) {
    // Resolve inputs by element count (all distinct).
    int ix[3] = {0, 1, 2}; int nx = 0;
    int iE = 3, iCol = 4, iRowI = 5, iRes = 6, iW = 8, iA1 = 9, iA2 = 10;
    bool a1seen = false;
    for (int i = 0; i < n_in; i++) {
        int s = in_sizes[i];
        if (s == NN * FIN) { if (nx < 3) ix[nx++] = i; }
        else if (s == 2 * NE) iE = i;
        else if (s == 2 * NN) iCol = i;
        else if (s == NN) iRowI = i;
        else if (s == NE) iRes = i;
        else if (s == FIN * FOUT) iW = i;
        else if (s == 2 * FOUT) { if (!a1seen) { iA1 = i; a1seen = true; } else iA2 = i; }
    }
    const float* input = (const float*)d_in[ix[0]];
    const float* p_h   = (const float*)d_in[ix[1]];
    const float* new_h = (const float*)d_in[ix[2]];
    const void* edge       = d_in[iE];
    const void* edge_col   = d_in[iCol];
    const void* row_i      = d_in[iRowI];
    const void* row_resort = d_in[iRes];
    const float* W  = (const float*)d_in[iW];
    const float* a1 = (const float*)d_in[iA1];
    const float* a2 = (const float*)d_in[iA2];

    // Outputs are FLOAT32, concatenated.
    float* out0 = (float*)d_out;                      // N*FOUT
    float* out1 = out0 + (size_t)NN * FOUT;           // 2*NE
    float* out2 = out1 + (size_t)2 * NE;              // NE (edge_e numerator, then in-place divide)

    // Coarse-scatter scratch: out1 region is free until k_final (last kernel).
    uint2* tmp = (uint2*)out1;

    // ws layout (~32 MB; h region reserved as NN*FOUT floats, used as bf16)
    unsigned short* h = (unsigned short*)d_ws;        // NN*FOUT bf16 (6.4 MB used)
    uint2*  spill  = (uint2*)((float*)d_ws + (size_t)NN * FOUT);  // NE uint2 (12.8 MB, skew fallback)
    float*  s1     = (float*)(spill + NE);
    float*  s2     = s1 + NN;
    float*  s4     = s2 + NN;
    float*  ec     = s4 + NN;                         // reused in place as ex
    float*  scf    = ec + NN;                         // float2[NN]: {s3, ecs}
    float*  mseg   = scf + 2 * (size_t)NN;            // zeroed (atomicMax uint bits)
    float*  ssum   = mseg + NN;                       // zeroed
    int*    bcnt   = (int*)(ssum + NN);               // NBK
    int*    bstart = bcnt + NBK;                      // NBK+1
    int*    cntm   = bstart + NBK + 1;                // NBLK*NBK (2.45 MB)
    int*    colpre = cntm + (size_t)NBLK * NBK;       // NBLK*NBK (2.45 MB)
    float*  ersum  = (float*)(colpre + (size_t)NBLK * NBK);  // NN
    float*  u      = ersum + NN;                      // 512
    int*    iflag  = (int*)(u + 512);

    hipMemsetAsync(mseg, 0, (size_t)2 * NN * sizeof(float), stream);  // mseg, ssum

    k_su<<<2, 256, 0, stream>>>((const int*)edge, iflag, W, a1, a2, u);
    k_gemm<<<NN / 16, 256, 0, stream>>>(input, W, h);
    k_svec_cnt<<<12500 + NBLK, 256, 0, stream>>>(input, p_h, new_h, u, s1, s2, scf, s4,
                                                 edge, iflag, cntm);
    k_colscore<<<(NN + 255) / 256, 256, 0, stream>>>(s1, s2, edge_col, row_i, iflag, ec, (unsigned int*)mseg);
    k_expsum<<<(NN + 255) / 256, 256, 0, stream>>>(ec, (const unsigned int*)mseg, row_i, iflag, ssum);
    k_norm<<<(NN + 255) / 256, 256, 0, stream>>>(ec, ssum, row_i, iflag, scf);
    k_colscan<<<NBK, 1024, 0, stream>>>(cntm, colpre, bcnt);
    k_bscan<<<1, 1024, 0, stream>>>(bcnt, bstart);
    k_edgeA<<<NBLK, 512, 0, stream>>>((const float2*)scf, s4, edge, row_resort, iflag, bstart, colpre, tmp, out2);
    k_aggB<<<NBK, 512, 0, stream>>>(h, tmp, bstart, spill, ersum, out0);
    k_final<<<2 * NE / 256, 256, 0, stream>>>(edge, iflag, ersum, out2, out1);
}

// Round 14
// 277.767 us; speedup vs baseline: 1.0202x; 1.0202x over previous
//
#include <hip/hip_runtime.h>

#define NN 50000
#define NE 1600000
#define FIN 128
#define FOUT 64
#define ALPHA 0.2f

#define RANGE 256          // destination nodes per bucket
#define NB 196             // ceil(NN / RANGE)
#define EPB 2048           // edges per block in pass A / cnt
#define NBLK 782           // ceil(NE / EPB)

typedef float v2f __attribute__((ext_vector_type(2)));

__device__ inline int ldi(const void* p, size_t i, int isi64) {
    int v = isi64 ? (int)((const long long*)p)[i] : ((const int*)p)[i];
    return v < 0 ? 0 : (v >= NN ? NN - 1 : v);  // clamp: no data-dependent OOB
}

// f32 -> bf16 round-to-nearest-even
__device__ inline unsigned short f2bf(float x) {
    unsigned u = __float_as_uint(x);
    return (unsigned short)((u + 0x7FFFu + ((u >> 16) & 1u)) >> 16);
}

// unpack uint (2 bf16) -> v2f {even, odd}
__device__ inline v2f bfu2(unsigned u) {
    v2f r;
    r.x = __uint_as_float(u << 16);
    r.y = __uint_as_float(u & 0xFFFF0000u);
    return r;
}

// ---------- K0: fused {int-width sniffer | u = W @ {a1l,a1r,a2l,a2r}} ----------
__global__ __launch_bounds__(256) void k_su(const int* __restrict__ edge32, int* __restrict__ iflag,
                                            const float* __restrict__ W, const float* __restrict__ a1,
                                            const float* __restrict__ a2, float* __restrict__ u) {
    if (blockIdx.x == 0) {
        __shared__ int zodd;
        if (threadIdx.x == 0) zodd = 0;
        __syncthreads();
        int z = 0;
        for (int i = threadIdx.x; i < 2048; i += 256)
            if (edge32[2 * i + 1] == 0) z++;    // int64 high words are always 0
        atomicAdd(&zodd, z);
        __syncthreads();
        if (threadIdx.x == 0) *iflag = (zodd > 2000) ? 1 : 0;
    } else {
        int k = threadIdx.x;  // 0..127 active
        if (k < FIN) {
            float u1 = 0.f, u2 = 0.f, u3 = 0.f, u4 = 0.f;
            for (int j = 0; j < FOUT; j++) {
                float w = W[k * FOUT + j];
                u1 += w * a1[j];
                u2 += w * a1[FOUT + j];
                u3 += w * a2[j];
                u4 += w * a2[FOUT + j];
            }
            u[k] = u1; u[128 + k] = u2; u[256 + k] = u3; u[384 + k] = u4;
        }
    }
}

// ---------- K1: h = input @ W  (N x 64, stored bf16 — consumed only by k_agg) ----------
__global__ __launch_bounds__(256) void k_gemm(const float* __restrict__ X,
                                              const float* __restrict__ W,
                                              unsigned short* __restrict__ h) {
    __shared__ float wlds[FIN * FOUT];      // 32 KB
    __shared__ float xlds[4][4][FIN];       // 8 KB
    int tid = threadIdx.x;
    for (int i = tid; i < FIN * FOUT; i += 256) wlds[i] = W[i];
    int wave = tid >> 6, lane = tid & 63;
    int base = blockIdx.x * 16 + wave * 4;  // 3125*16 = 50000 exact
    for (int n0 = 0; n0 < 4; n0++) {
        float2 b = ((const float2*)(X + (size_t)(base + n0) * FIN))[lane];
        xlds[wave][n0][2 * lane] = b.x;
        xlds[wave][n0][2 * lane + 1] = b.y;
    }
    __syncthreads();
    float a0 = 0.f, a1v = 0.f, a2v = 0.f, a3 = 0.f;
    for (int k = 0; k < FIN; k++) {
        float w = wlds[k * FOUT + lane];
        a0  += xlds[wave][0][k] * w;
        a1v += xlds[wave][1][k] * w;
        a2v += xlds[wave][2][k] * w;
        a3  += xlds[wave][3][k] * w;
    }
    h[(size_t)(base + 0) * FOUT + lane] = f2bf(a0);
    h[(size_t)(base + 1) * FOUT + lane] = f2bf(a1v);
    h[(size_t)(base + 2) * FOUT + lane] = f2bf(a2v);
    h[(size_t)(base + 3) * FOUT + lane] = f2bf(a3);
}

// ---------- K1b: fused {per-node score scalars | per-block bucket counts} ----------
__global__ __launch_bounds__(256) void k_svec_cnt(const float* __restrict__ input,
                                                  const float* __restrict__ p_h,
                                                  const float* __restrict__ new_h,
                                                  const float* __restrict__ u,
                                                  float* __restrict__ s1, float* __restrict__ s2,
                                                  float* __restrict__ sc /* float2 as float* */,
                                                  float* __restrict__ s4,
                                                  const void* __restrict__ edge,
                                                  const int* __restrict__ iflag,
                                                  int* __restrict__ cntm) {
    __shared__ int hist[NB];
    int tid = threadIdx.x;
    if (blockIdx.x < 12500) {
        int lane = tid & 63;
        int v = blockIdx.x * 4 + (tid >> 6);
        size_t row = (size_t)v * FIN;
        float2 bi = ((const float2*)(input + row))[lane];
        float2 bp = ((const float2*)(p_h   + row))[lane];
        float2 bn = ((const float2*)(new_h + row))[lane];
        float p1 = bi.x * u[2 * lane]       + bi.y * u[2 * lane + 1];
        float p2 = bp.x * u[128 + 2 * lane] + bp.y * u[128 + 2 * lane + 1];
        float p3 = bn.x * u[256 + 2 * lane] + bn.y * u[256 + 2 * lane + 1];
        float p4 = bi.x * u[384 + 2 * lane] + bi.y * u[384 + 2 * lane + 1];
#pragma unroll
        for (int off = 32; off > 0; off >>= 1) {
            p1 += __shfl_down(p1, off, 64);
            p2 += __shfl_down(p2, off, 64);
            p3 += __shfl_down(p3, off, 64);
            p4 += __shfl_down(p4, off, 64);
        }
        if (lane == 0) { s1[v] = p1; s2[v] = p2; sc[2 * v] = p3; s4[v] = p4; }
    } else {
        int cb = blockIdx.x - 12500;                  // 0..781
        for (int t = tid; t < NB; t += 256) hist[t] = 0;
        __syncthreads();
        int i64 = *iflag;
        int base = cb * EPB;
        int b0[8]; bool act[8];
#pragma unroll
        for (int k = 0; k < 8; k++) {                 // phase 1: 8 independent loads
            int e = base + k * 256 + tid;
            act[k] = e < NE;
            b0[k] = ldi(edge, act[k] ? e : NE - 1, i64) >> 8;
        }
#pragma unroll
        for (int k = 0; k < 8; k++)                   // phase 2: 8 LDS atomics
            if (act[k]) atomicAdd(&hist[b0[k]], 1);
        __syncthreads();
        for (int t = tid; t < NB; t += 256)
            cntm[cb * NB + t] = hist[t];              // plain coalesced row store
    }
}

// ---------- K2: col score + exp + segment max ----------
__global__ void k_colscore(const float* __restrict__ s1, const float* __restrict__ s2,
                           const void* __restrict__ edge_col, const void* __restrict__ row_i,
                           const int* __restrict__ iflag,
                           float* __restrict__ ec, unsigned int* __restrict__ m) {
    int i = blockIdx.x * 256 + threadIdx.x;
    if (i >= NN) return;
    int i64 = *iflag;
    float cs = s1[ldi(edge_col, i, i64)] + s2[i];
    float l = cs > 0.f ? cs : ALPHA * cs;
    float e = expf(-l);                // > 0 always
    ec[i] = e;
    atomicMax(&m[ldi(row_i, i, i64)], __float_as_uint(e));  // init 0, e>0 -> valid
}

// ---------- K3: ex = exp(ec - m) in place; segment sum ----------
__global__ void k_expsum(float* __restrict__ ec, const unsigned int* __restrict__ m,
                         const void* __restrict__ row_i, const int* __restrict__ iflag,
                         float* __restrict__ ssum) {
    int i = blockIdx.x * 256 + threadIdx.x;
    if (i >= NN) return;
    int r = ldi(row_i, i, *iflag);
    float e = expf(ec[i] - __uint_as_float(m[r]));
    ec[i] = e;
    atomicAdd(&ssum[r], e);
}

// ---------- K4: normalize -> sc[i].y = ecs ----------
__global__ void k_norm(const float* __restrict__ ex, const float* __restrict__ ssum,
                       const void* __restrict__ row_i, const int* __restrict__ iflag,
                       float* __restrict__ sc /* float2 as float* */) {
    int i = blockIdx.x * 256 + threadIdx.x;
    if (i >= NN) return;
    sc[2 * i + 1] = ex[i] / (ssum[ldi(row_i, i, *iflag)] + 1e-16f);
}

// ---------- K5b1: per-bucket column scan over 782 blocks -> colpre, bcnt ----------
__global__ __launch_bounds__(1024) void k_colscan(const int* __restrict__ cntm,
                                                  int* __restrict__ colpre,
                                                  int* __restrict__ bcnt) {
    __shared__ int s[1024];
    int b = blockIdx.x, tid = threadIdx.x;
    int x = (tid < NBLK) ? cntm[(size_t)tid * NB + b] : 0;
    s[tid] = x;
    __syncthreads();
    for (int off = 1; off < 1024; off <<= 1) {
        int t = (tid >= off) ? s[tid - off] : 0;
        __syncthreads();
        s[tid] += t;
        __syncthreads();
    }
    if (tid < NBLK) colpre[(size_t)tid * NB + b] = s[tid] - x;  // exclusive within column
    if (tid == 1023) bcnt[b] = s[1023];                         // column total
}

// ---------- K5b2: scan 196 bucket totals -> bstart; sentinels ----------
__global__ __launch_bounds__(256) void k_bscan(const int* __restrict__ bcnt,
                                               int* __restrict__ bstart,
                                               int* __restrict__ start) {
    __shared__ int s[256];
    int tid = threadIdx.x;
    int x = (tid < NB) ? bcnt[tid] : 0;
    s[tid] = x;
    __syncthreads();
    for (int off = 1; off < 256; off <<= 1) {
        int t = (tid >= off) ? s[tid - off] : 0;
        __syncthreads();
        s[tid] += t;
        __syncthreads();
    }
    if (tid < NB) bstart[tid] = s[tid] - x;
    if (tid == 0) { bstart[NB] = NE; start[NN] = NE; }
}

// ---------- K5c pass A: explicit-MLP phase-split; single barrier ----------
__global__ __launch_bounds__(512) void k_edgeA(const float2* __restrict__ sc, const float* __restrict__ s4,
                                               const void* __restrict__ edge, const void* __restrict__ row_resort,
                                               const int* __restrict__ iflag,
                                               const int* __restrict__ bstart, const int* __restrict__ colpre,
                                               uint2* __restrict__ tmp,
                                               float* __restrict__ edge_e /* = out2 */) {
    __shared__ int hist[NB];
    __shared__ int bbase[NB];
    int tid = threadIdx.x;
    for (int t = tid; t < NB; t += 512) {
        hist[t] = 0;
        bbase[t] = bstart[t] + colpre[(size_t)blockIdx.x * NB + t];  // prefetch, hist-independent
    }
    __syncthreads();
    int i64 = *iflag;
    int base = blockIdx.x * EPB;
    int e0[4], e1[4], rr[4]; bool act[4];
#pragma unroll
    for (int k = 0; k < 4; k++) {                     // phase 1: 12 independent index loads
        int e = base + k * 512 + tid;
        act[k] = e < NE;
        size_t ec = act[k] ? (size_t)e : (size_t)(NE - 1);  // clamped: loads always legal
        e0[k] = ldi(edge, ec, i64);
        e1[k] = ldi(edge, (size_t)NE + ec, i64);
        rr[k] = ldi(row_resort, ec, i64);
    }
    float2 c[4]; float s4v[4];
#pragma unroll
    for (int k = 0; k < 4; k++) {                     // phase 2: 8 independent gathers
        c[k] = sc[rr[k]];
        s4v[k] = s4[e1[k]];
    }
    unsigned key[4]; float val[4]; int rk[4], bk[4];
#pragma unroll
    for (int k = 0; k < 4; k++) {                     // phase 3: compute + rank + numerator
        float rsv = c[k].x + s4v[k];
        float l = rsv > 0.f ? rsv : ALPHA * rsv;
        float ee = expf(-l) * c[k].y;
        if (act[k]) edge_e[base + k * 512 + tid] = ee;
        key[k] = (unsigned)e0[k] | ((unsigned)e1[k] << 16);   // both < 65536
        val[k] = ee;
        bk[k] = e0[k] >> 8;                           // bucket = e0 / RANGE
        rk[k] = act[k] ? atomicAdd(&hist[bk[k]], 1) : 0;      // rank within (block,bucket)
    }
#pragma unroll
    for (int k = 0; k < 4; k++)                       // scatter: no barrier needed
        if (act[k])
            tmp[bbase[bk[k]] + rk[k]] = make_uint2(key[k], __float_as_uint(val[k]));
}

// ---------- K5c pass B: per-node offsets + fine scatter, L2-resident ----------
__global__ __launch_bounds__(512) void k_edgeB(const uint2* __restrict__ tmp,
                                               const int* __restrict__ bstart,
                                               int* __restrict__ start,
                                               float2* __restrict__ pairs) {
    __shared__ int cnt[RANGE];
    __shared__ int s[RANGE];
    __shared__ int cur[RANGE];
    int b = blockIdx.x;
    int tid = threadIdx.x;
    int v0 = b * RANGE;
    if (tid < RANGE) cnt[tid] = 0;
    __syncthreads();
    int lo = bstart[b], hi = bstart[b + 1];
    for (int i = lo + tid; i < hi; i += 512)
        atomicAdd(&cnt[tmp[i].x & 0xFFu], 1);         // e0 & 255 == e0 - v0
    __syncthreads();
    if (tid < RANGE) s[tid] = cnt[tid];
    __syncthreads();
    for (int off = 1; off < RANGE; off <<= 1) {
        int t = 0;
        if (tid < RANGE && tid >= off) t = s[tid - off];
        __syncthreads();
        if (tid < RANGE) s[tid] += t;
        __syncthreads();
    }
    if (tid < RANGE) {
        int g = lo + s[tid] - cnt[tid];               // exclusive prefix + bucket base
        cur[tid] = g;
        int v = v0 + tid;
        if (v < NN) start[v] = g;
    }
    __syncthreads();
    for (int i = lo + tid; i < hi; i += 512) {
        uint2 r = tmp[i];
        int pos = atomicAdd(&cur[r.x & 0xFFu], 1);    // LDS atomic
        pairs[pos] = make_float2(__int_as_float((int)(r.x >> 16)), __uint_as_float(r.y));
    }
}

// ---------- K6: gather-aggregate; packed accumulators + software-pipelined pairs ----------
// pairs[j+16] for the NEXT iteration is loaded while the CURRENT iteration's
// h-gathers are in flight, overlapping the first hop of the two-level dependent
// chain (pairs -> h). Loop bounds are wave-uniform (per-node), so the pipeline
// branches don't diverge.
__global__ __launch_bounds__(512) void k_agg(const unsigned short* __restrict__ h,
                                             const float2* __restrict__ pairs,
                                             const int* __restrict__ start,
                                             float* __restrict__ ersum,
                                             float* __restrict__ out0) {
    int lane = threadIdx.x & 63;
    int q  = lane >> 3;                // edge slot 0..7
    int fq = lane & 7;                 // feature octet: feats 8fq..8fq+7
    int v = blockIdx.x * 8 + (threadIdx.x >> 6);      // 6250*8 = NN exact
    int a = start[v], b = start[v + 1];
    v2f a01 = {0.f, 0.f}, a23 = {0.f, 0.f}, a45 = {0.f, 0.f}, a67 = {0.f, 0.f};
    float rs = 0.f;
    int bfull = a + ((b - a) & ~15);
    int j = a;
    float2 pA, pB;
    if (j < bfull) { pA = pairs[j + q]; pB = pairs[j + 8 + q]; }   // prologue
    for (; j < bfull; j += 16) {
        // issue h gathers for current pair immediately (pairs already resident)
        uint4 hA = *(const uint4*)(h + (((size_t)__float_as_int(pA.x)) << 6) + 8 * fq);
        uint4 hB = *(const uint4*)(h + (((size_t)__float_as_int(pB.x)) << 6) + 8 * fq);
        // prefetch next iteration's pairs while h gathers are in flight
        int jn = j + 16;
        float2 nA, nB;
        if (jn < bfull) { nA = pairs[jn + q]; nB = pairs[jn + 8 + q]; }
        v2f eA = {pA.y, pA.y}, eB = {pB.y, pB.y};
        a01 += eA * bfu2(hA.x);
        a23 += eA * bfu2(hA.y);
        a45 += eA * bfu2(hA.z);
        a67 += eA * bfu2(hA.w);
        a01 += eB * bfu2(hB.x);
        a23 += eB * bfu2(hB.y);
        a45 += eB * bfu2(hB.z);
        a67 += eB * bfu2(hB.w);
        rs += pA.y + pB.y;
        if (jn < bfull) { pA = nA; pB = nB; }
    }
    if (j < b) {                                      // guarded tail, single pass
        int eAi = j + q, eBi = j + 8 + q;
        float2 tA = (eAi < b) ? pairs[eAi] : make_float2(__int_as_float(0), 0.f);
        float2 tB = (eBi < b) ? pairs[eBi] : make_float2(__int_as_float(0), 0.f);
        uint4 hA = *(const uint4*)(h + (((size_t)__float_as_int(tA.x)) << 6) + 8 * fq);
        uint4 hB = *(const uint4*)(h + (((size_t)__float_as_int(tB.x)) << 6) + 8 * fq);
        v2f eA = {tA.y, tA.y}, eB = {tB.y, tB.y};
        a01 += eA * bfu2(hA.x);
        a23 += eA * bfu2(hA.y);
        a45 += eA * bfu2(hA.z);
        a67 += eA * bfu2(hA.w);
        a01 += eB * bfu2(hB.x);
        a23 += eB * bfu2(hB.y);
        a45 += eB * bfu2(hB.z);
        a67 += eB * bfu2(hB.w);
        rs += tA.y + tB.y;
    }
#pragma unroll
    for (int off = 8; off <= 32; off <<= 1) {         // reduce across edge slots (q bits)
        v2f t01, t23, t45, t67;
        t01.x = __shfl_xor(a01.x, off, 64); t01.y = __shfl_xor(a01.y, off, 64);
        t23.x = __shfl_xor(a23.x, off, 64); t23.y = __shfl_xor(a23.y, off, 64);
        t45.x = __shfl_xor(a45.x, off, 64); t45.y = __shfl_xor(a45.y, off, 64);
        t67.x = __shfl_xor(a67.x, off, 64); t67.y = __shfl_xor(a67.y, off, 64);
        a01 += t01; a23 += t23; a45 += t45; a67 += t67;
        rs  += __shfl_xor(rs, off, 64);
    }
    // one result per lane: keep feature 8*fq + q (pair q>>1, component q&1)
    v2f ap = (q >> 1) == 0 ? a01 : (q >> 1) == 1 ? a23 : (q >> 1) == 2 ? a45 : a67;
    float av = (q & 1) ? ap.y : ap.x;
    rs += (rs == 0.f) ? 1.f : 0.f;                    // empty-segment fixup (ee>0 otherwise)
    float ev = av / rs;
    ev = ev > 0.f ? ev : expm1f(ev);
    out0[(size_t)v * FOUT + 8 * fq + q] = ev;         // permuted within 256B row
    if (lane == 0) ersum[v] = rs;                     // fixed rowsum, plain store
}

// ---------- K7: out1 = float(edge) AND out2 /= ersum[e0] (fused, runs LAST) ----------
__global__ __launch_bounds__(256) void k_final(const void* __restrict__ edge, const int* __restrict__ iflag,
                                               const float* __restrict__ ersum,
                                               float* __restrict__ out2, float* __restrict__ out1) {
    int i = blockIdx.x * 256 + threadIdx.x;           // 12500*256 = 2*NE exact
    int i64 = *iflag;
    int v = i64 ? (int)((const long long*)edge)[i] : ((const int*)edge)[i];
    out1[i] = (float)v;
    if (i < NE) {                                     // edge[0..NE) is row 0 = e0
        int e0 = v < 0 ? 0 : (v >= NN ? NN - 1 : v);
        out2[i] = out2[i] / ersum[e0];
    }
}

extern "C" void kernel_launch(void* const* d_in, const int* in_sizes, int n_in,
                              void* d_out, int out_size, void* d_ws, size_t ws_size,
                              hipStream_t stream) {
    // Resolve inputs by element count (all distinct).
    int ix[3] = {0, 1, 2}; int nx = 0;
    int iE = 3, iCol = 4, iRowI = 5, iRes = 6, iW = 8, iA1 = 9, iA2 = 10;
    bool a1seen = false;
    for (int i = 0; i < n_in; i++) {
        int s = in_sizes[i];
        if (s == NN * FIN) { if (nx < 3) ix[nx++] = i; }
        else if (s == 2 * NE) iE = i;
        else if (s == 2 * NN) iCol = i;
        else if (s == NN) iRowI = i;
        else if (s == NE) iRes = i;
        else if (s == FIN * FOUT) iW = i;
        else if (s == 2 * FOUT) { if (!a1seen) { iA1 = i; a1seen = true; } else iA2 = i; }
    }
    const float* input = (const float*)d_in[ix[0]];
    const float* p_h   = (const float*)d_in[ix[1]];
    const float* new_h = (const float*)d_in[ix[2]];
    const void* edge       = d_in[iE];
    const void* edge_col   = d_in[iCol];
    const void* row_i      = d_in[iRowI];
    const void* row_resort = d_in[iRes];
    const float* W  = (const float*)d_in[iW];
    const float* a1 = (const float*)d_in[iA1];
    const float* a2 = (const float*)d_in[iA2];

    // Outputs are FLOAT32, concatenated.
    float* out0 = (float*)d_out;                      // N*FOUT
    float* out1 = out0 + (size_t)NN * FOUT;           // 2*NE
    float* out2 = out1 + (size_t)2 * NE;              // NE (edge_e numerator, then in-place divide)

    // Coarse-scatter scratch: out1 region is free until k_final (last kernel).
    uint2* tmp = (uint2*)out1;

    // ws layout (~29 MB; h region reserved as NN*FOUT floats, used as bf16)
    unsigned short* h = (unsigned short*)d_ws;        // NN*FOUT bf16 (6.4 MB used)
    float2* pairs  = (float2*)((float*)d_ws + (size_t)NN * FOUT); // NE float2 (12.8 MB)
    float*  s1     = (float*)(pairs + NE);
    float*  s2     = s1 + NN;
    float*  s4     = s2 + NN;
    float*  ec     = s4 + NN;                         // reused in place as ex
    float*  scf    = ec + NN;                         // float2[NN]: {s3, ecs}
    float*  mseg   = scf + 2 * (size_t)NN;            // zeroed (atomicMax uint bits)
    float*  ssum   = mseg + NN;                       // zeroed
    int*    bcnt   = (int*)(ssum + NN);               // NB
    int*    start  = bcnt + NB;                       // NN+1 (sentinel)
    int*    bstart = start + NN + 1;                  // NB+1
    int*    cntm   = bstart + NB + 1;                 // NBLK*NB (613 KB)
    int*    colpre = cntm + (size_t)NBLK * NB;        // NBLK*NB (613 KB)
    float*  ersum  = (float*)(colpre + (size_t)NBLK * NB);  // NN
    float*  u      = ersum + NN;                      // 512
    int*    iflag  = (int*)(u + 512);

    hipMemsetAsync(mseg, 0, (size_t)2 * NN * sizeof(float), stream);  // mseg, ssum

    k_su<<<2, 256, 0, stream>>>((const int*)edge, iflag, W, a1, a2, u);
    k_gemm<<<NN / 16, 256, 0, stream>>>(input, W, h);
    k_svec_cnt<<<12500 + NBLK, 256, 0, stream>>>(input, p_h, new_h, u, s1, s2, scf, s4,
                                                 edge, iflag, cntm);
    k_colscore<<<(NN + 255) / 256, 256, 0, stream>>>(s1, s2, edge_col, row_i, iflag, ec, (unsigned int*)mseg);
    k_expsum<<<(NN + 255) / 256, 256, 0, stream>>>(ec, (const unsigned int*)mseg, row_i, iflag, ssum);
    k_norm<<<(NN + 255) / 256, 256, 0, stream>>>(ec, ssum, row_i, iflag, scf);
    k_colscan<<<NB, 1024, 0, stream>>>(cntm, colpre, bcnt);
    k_bscan<<<1, 256, 0, stream>>>(bcnt, bstart, start);
    k_edgeA<<<NBLK, 512, 0, stream>>>((const float2*)scf, s4, edge, row_resort, iflag, bstart, colpre, tmp, out2);
    k_edgeB<<<NB, 512, 0, stream>>>(tmp, bstart, start, pairs);
    k_agg<<<NN / 8, 512, 0, stream>>>(h, pairs, start, ersum, out0);
    k_final<<<2 * NE / 256, 256, 0, stream>>>(edge, iflag, ersum, out2, out1);
}

// Round 15
// 274.791 us; speedup vs baseline: 1.0312x; 1.0108x over previous
//
#include <hip/hip_runtime.h>

#define NN 50000
#define NE 1600000
#define FIN 128
#define FOUT 64
#define ALPHA 0.2f

#define RANGE 256          // destination nodes per bucket
#define NB 196             // ceil(NN / RANGE)
#define EPB 2048           // edges per block in pass A / cnt
#define NBLK 782           // ceil(NE / EPB)
#define ACAP 1024          // k_agg LDS pairs capacity (mean 256/block, sigma~16)

typedef float v2f __attribute__((ext_vector_type(2)));

__device__ inline int ldi(const void* p, size_t i, int isi64) {
    int v = isi64 ? (int)((const long long*)p)[i] : ((const int*)p)[i];
    return v < 0 ? 0 : (v >= NN ? NN - 1 : v);  // clamp: no data-dependent OOB
}

// f32 -> bf16 round-to-nearest-even
__device__ inline unsigned short f2bf(float x) {
    unsigned u = __float_as_uint(x);
    return (unsigned short)((u + 0x7FFFu + ((u >> 16) & 1u)) >> 16);
}

// unpack uint (2 bf16) -> v2f {even, odd}
__device__ inline v2f bfu2(unsigned u) {
    v2f r;
    r.x = __uint_as_float(u << 16);
    r.y = __uint_as_float(u & 0xFFFF0000u);
    return r;
}

// ---------- K1: fused {h = input @ W (bf16 out) | sniffer | u} ----------
// Blocks [0,3125): gemm tiles. Block 3125: int-width sniffer. Block 3126: u.
__global__ __launch_bounds__(256) void k_gemm_su(const float* __restrict__ X,
                                                 const float* __restrict__ W,
                                                 unsigned short* __restrict__ h,
                                                 const int* __restrict__ edge32, int* __restrict__ iflag,
                                                 const float* __restrict__ a1,
                                                 const float* __restrict__ a2, float* __restrict__ u) {
    __shared__ float wlds[FIN * FOUT];      // 32 KB
    __shared__ float xlds[4][4][FIN];       // 8 KB
    int tid = threadIdx.x;
    if (blockIdx.x >= NN / 16) {
        if (blockIdx.x == NN / 16) {                  // sniffer
            __shared__ int zodd;
            if (tid == 0) zodd = 0;
            __syncthreads();
            int z = 0;
            for (int i = tid; i < 2048; i += 256)
                if (edge32[2 * i + 1] == 0) z++;      // int64 high words are always 0
            atomicAdd(&zodd, z);
            __syncthreads();
            if (tid == 0) *iflag = (zodd > 2000) ? 1 : 0;
        } else {                                      // u = W @ {a1l,a1r,a2l,a2r}
            int k = tid;
            if (k < FIN) {
                float u1 = 0.f, u2 = 0.f, u3 = 0.f, u4 = 0.f;
                for (int j = 0; j < FOUT; j++) {
                    float w = W[k * FOUT + j];
                    u1 += w * a1[j];
                    u2 += w * a1[FOUT + j];
                    u3 += w * a2[j];
                    u4 += w * a2[FOUT + j];
                }
                u[k] = u1; u[128 + k] = u2; u[256 + k] = u3; u[384 + k] = u4;
            }
        }
        return;
    }
    for (int i = tid; i < FIN * FOUT; i += 256) wlds[i] = W[i];
    int wave = tid >> 6, lane = tid & 63;
    int base = blockIdx.x * 16 + wave * 4;  // 3125*16 = 50000 exact
    for (int n0 = 0; n0 < 4; n0++) {
        float2 b = ((const float2*)(X + (size_t)(base + n0) * FIN))[lane];
        xlds[wave][n0][2 * lane] = b.x;
        xlds[wave][n0][2 * lane + 1] = b.y;
    }
    __syncthreads();
    float a0 = 0.f, a1v = 0.f, a2v = 0.f, a3 = 0.f;
    for (int k = 0; k < FIN; k++) {
        float w = wlds[k * FOUT + lane];
        a0  += xlds[wave][0][k] * w;
        a1v += xlds[wave][1][k] * w;
        a2v += xlds[wave][2][k] * w;
        a3  += xlds[wave][3][k] * w;
    }
    h[(size_t)(base + 0) * FOUT + lane] = f2bf(a0);
    h[(size_t)(base + 1) * FOUT + lane] = f2bf(a1v);
    h[(size_t)(base + 2) * FOUT + lane] = f2bf(a2v);
    h[(size_t)(base + 3) * FOUT + lane] = f2bf(a3);
}

// ---------- K1b: fused {per-node score scalars | per-block bucket counts} ----------
__global__ __launch_bounds__(256) void k_svec_cnt(const float* __restrict__ input,
                                                  const float* __restrict__ p_h,
                                                  const float* __restrict__ new_h,
                                                  const float* __restrict__ u,
                                                  float* __restrict__ s1, float* __restrict__ s2,
                                                  float* __restrict__ sc /* float2 as float* */,
                                                  float* __restrict__ s4,
                                                  const void* __restrict__ edge,
                                                  const int* __restrict__ iflag,
                                                  int* __restrict__ cntm) {
    __shared__ int hist[NB];
    int tid = threadIdx.x;
    if (blockIdx.x < 12500) {
        int lane = tid & 63;
        int v = blockIdx.x * 4 + (tid >> 6);
        size_t row = (size_t)v * FIN;
        float2 bi = ((const float2*)(input + row))[lane];
        float2 bp = ((const float2*)(p_h   + row))[lane];
        float2 bn = ((const float2*)(new_h + row))[lane];
        float p1 = bi.x * u[2 * lane]       + bi.y * u[2 * lane + 1];
        float p2 = bp.x * u[128 + 2 * lane] + bp.y * u[128 + 2 * lane + 1];
        float p3 = bn.x * u[256 + 2 * lane] + bn.y * u[256 + 2 * lane + 1];
        float p4 = bi.x * u[384 + 2 * lane] + bi.y * u[384 + 2 * lane + 1];
#pragma unroll
        for (int off = 32; off > 0; off >>= 1) {
            p1 += __shfl_down(p1, off, 64);
            p2 += __shfl_down(p2, off, 64);
            p3 += __shfl_down(p3, off, 64);
            p4 += __shfl_down(p4, off, 64);
        }
        if (lane == 0) { s1[v] = p1; s2[v] = p2; sc[2 * v] = p3; s4[v] = p4; }
    } else {
        int cb = blockIdx.x - 12500;                  // 0..781
        for (int t = tid; t < NB; t += 256) hist[t] = 0;
        __syncthreads();
        int i64 = *iflag;
        int base = cb * EPB;
        int b0[8]; bool act[8];
#pragma unroll
        for (int k = 0; k < 8; k++) {                 // phase 1: 8 independent loads
            int e = base + k * 256 + tid;
            act[k] = e < NE;
            b0[k] = ldi(edge, act[k] ? e : NE - 1, i64) >> 8;
        }
#pragma unroll
        for (int k = 0; k < 8; k++)                   // phase 2: 8 LDS atomics
            if (act[k]) atomicAdd(&hist[b0[k]], 1);
        __syncthreads();
        for (int t = tid; t < NB; t += 256)
            cntm[cb * NB + t] = hist[t];              // plain coalesced row store
    }
}

// ---------- K2: col score + exp + segment max ----------
__global__ void k_colscore(const float* __restrict__ s1, const float* __restrict__ s2,
                           const void* __restrict__ edge_col, const void* __restrict__ row_i,
                           const int* __restrict__ iflag,
                           float* __restrict__ ec, unsigned int* __restrict__ m) {
    int i = blockIdx.x * 256 + threadIdx.x;
    if (i >= NN) return;
    int i64 = *iflag;
    float cs = s1[ldi(edge_col, i, i64)] + s2[i];
    float l = cs > 0.f ? cs : ALPHA * cs;
    float e = expf(-l);                // > 0 always
    ec[i] = e;
    atomicMax(&m[ldi(row_i, i, i64)], __float_as_uint(e));  // init 0, e>0 -> valid
}

// ---------- K3: ex = exp(ec - m) in place; segment sum ----------
__global__ void k_expsum(float* __restrict__ ec, const unsigned int* __restrict__ m,
                         const void* __restrict__ row_i, const int* __restrict__ iflag,
                         float* __restrict__ ssum) {
    int i = blockIdx.x * 256 + threadIdx.x;
    if (i >= NN) return;
    int r = ldi(row_i, i, *iflag);
    float e = expf(ec[i] - __uint_as_float(m[r]));
    ec[i] = e;
    atomicAdd(&ssum[r], e);
}

// ---------- K4: normalize -> sc[i].y = ecs ----------
__global__ void k_norm(const float* __restrict__ ex, const float* __restrict__ ssum,
                       const void* __restrict__ row_i, const int* __restrict__ iflag,
                       float* __restrict__ sc /* float2 as float* */) {
    int i = blockIdx.x * 256 + threadIdx.x;
    if (i >= NN) return;
    sc[2 * i + 1] = ex[i] / (ssum[ldi(row_i, i, *iflag)] + 1e-16f);
}

// ---------- K5b1: per-bucket column scan over 782 blocks -> colpre, bcnt ----------
__global__ __launch_bounds__(1024) void k_colscan(const int* __restrict__ cntm,
                                                  int* __restrict__ colpre,
                                                  int* __restrict__ bcnt) {
    __shared__ int s[1024];
    int b = blockIdx.x, tid = threadIdx.x;
    int x = (tid < NBLK) ? cntm[(size_t)tid * NB + b] : 0;
    s[tid] = x;
    __syncthreads();
    for (int off = 1; off < 1024; off <<= 1) {
        int t = (tid >= off) ? s[tid - off] : 0;
        __syncthreads();
        s[tid] += t;
        __syncthreads();
    }
    if (tid < NBLK) colpre[(size_t)tid * NB + b] = s[tid] - x;  // exclusive within column
    if (tid == 1023) bcnt[b] = s[1023];                         // column total
}

// ---------- K5b2: scan 196 bucket totals -> bstart; sentinels ----------
__global__ __launch_bounds__(256) void k_bscan(const int* __restrict__ bcnt,
                                               int* __restrict__ bstart,
                                               int* __restrict__ start) {
    __shared__ int s[256];
    int tid = threadIdx.x;
    int x = (tid < NB) ? bcnt[tid] : 0;
    s[tid] = x;
    __syncthreads();
    for (int off = 1; off < 256; off <<= 1) {
        int t = (tid >= off) ? s[tid - off] : 0;
        __syncthreads();
        s[tid] += t;
        __syncthreads();
    }
    if (tid < NB) bstart[tid] = s[tid] - x;
    if (tid == 0) { bstart[NB] = NE; start[NN] = NE; }
}

// ---------- K5c pass A: explicit-MLP phase-split; single barrier ----------
__global__ __launch_bounds__(512) void k_edgeA(const float2* __restrict__ sc, const float* __restrict__ s4,
                                               const void* __restrict__ edge, const void* __restrict__ row_resort,
                                               const int* __restrict__ iflag,
                                               const int* __restrict__ bstart, const int* __restrict__ colpre,
                                               uint2* __restrict__ tmp,
                                               float* __restrict__ edge_e /* = out2 */) {
    __shared__ int hist[NB];
    __shared__ int bbase[NB];
    int tid = threadIdx.x;
    for (int t = tid; t < NB; t += 512) {
        hist[t] = 0;
        bbase[t] = bstart[t] + colpre[(size_t)blockIdx.x * NB + t];  // prefetch, hist-independent
    }
    __syncthreads();
    int i64 = *iflag;
    int base = blockIdx.x * EPB;
    int e0[4], e1[4], rr[4]; bool act[4];
#pragma unroll
    for (int k = 0; k < 4; k++) {                     // phase 1: 12 independent index loads
        int e = base + k * 512 + tid;
        act[k] = e < NE;
        size_t ec = act[k] ? (size_t)e : (size_t)(NE - 1);  // clamped: loads always legal
        e0[k] = ldi(edge, ec, i64);
        e1[k] = ldi(edge, (size_t)NE + ec, i64);
        rr[k] = ldi(row_resort, ec, i64);
    }
    float2 c[4]; float s4v[4];
#pragma unroll
    for (int k = 0; k < 4; k++) {                     // phase 2: 8 independent gathers
        c[k] = sc[rr[k]];
        s4v[k] = s4[e1[k]];
    }
    unsigned key[4]; float val[4]; int rk[4], bk[4];
#pragma unroll
    for (int k = 0; k < 4; k++) {                     // phase 3: compute + rank + numerator
        float rsv = c[k].x + s4v[k];
        float l = rsv > 0.f ? rsv : ALPHA * rsv;
        float ee = expf(-l) * c[k].y;
        if (act[k]) edge_e[base + k * 512 + tid] = ee;
        key[k] = (unsigned)e0[k] | ((unsigned)e1[k] << 16);   // both < 65536
        val[k] = ee;
        bk[k] = e0[k] >> 8;                           // bucket = e0 / RANGE
        rk[k] = act[k] ? atomicAdd(&hist[bk[k]], 1) : 0;      // rank within (block,bucket)
    }
#pragma unroll
    for (int k = 0; k < 4; k++)                       // scatter: no barrier needed
        if (act[k])
            tmp[bbase[bk[k]] + rk[k]] = make_uint2(key[k], __float_as_uint(val[k]));
}

// ---------- K5c pass B: per-node offsets + fine scatter, L2-resident ----------
__global__ __launch_bounds__(512) void k_edgeB(const uint2* __restrict__ tmp,
                                               const int* __restrict__ bstart,
                                               int* __restrict__ start,
                                               float2* __restrict__ pairs) {
    __shared__ int cnt[RANGE];
    __shared__ int s[RANGE];
    __shared__ int cur[RANGE];
    int b = blockIdx.x;
    int tid = threadIdx.x;
    int v0 = b * RANGE;
    if (tid < RANGE) cnt[tid] = 0;
    __syncthreads();
    int lo = bstart[b], hi = bstart[b + 1];
    for (int i = lo + tid; i < hi; i += 512)
        atomicAdd(&cnt[tmp[i].x & 0xFFu], 1);         // e0 & 255 == e0 - v0
    __syncthreads();
    if (tid < RANGE) s[tid] = cnt[tid];
    __syncthreads();
    for (int off = 1; off < RANGE; off <<= 1) {
        int t = 0;
        if (tid < RANGE && tid >= off) t = s[tid - off];
        __syncthreads();
        if (tid < RANGE) s[tid] += t;
        __syncthreads();
    }
    if (tid < RANGE) {
        int g = lo + s[tid] - cnt[tid];               // exclusive prefix + bucket base
        cur[tid] = g;
        int v = v0 + tid;
        if (v < NN) start[v] = g;
    }
    __syncthreads();
    for (int i = lo + tid; i < hi; i += 512) {
        uint2 r = tmp[i];
        int pos = atomicAdd(&cur[r.x & 0xFFu], 1);    // LDS atomic
        pairs[pos] = make_float2(__int_as_float((int)(r.x >> 16)), __uint_as_float(r.y));
    }
}

// ---------- K6: gather-aggregate; LDS-staged pairs slice + packed accumulators ----------
// The block's pairs range [start[v0], start[v0+8]) is CONTIGUOUS (avg 256
// records). Stage it into 8 KB LDS with coalesced loads; the first hop of the
// dependent chain (pairs -> h address) becomes an LDS read (~30 cy) instead of
// an L2 hit (~200 cy). Overflow (>ACAP, practically never at sigma~16) falls
// back to direct global reads via a generic pointer — identical math.
__global__ __launch_bounds__(512) void k_agg(const unsigned short* __restrict__ h,
                                             const float2* __restrict__ pairs,
                                             const int* __restrict__ start,
                                             float* __restrict__ ersum,
                                             float* __restrict__ out0) {
    __shared__ float2 lp[ACAP];                       // 8 KB
    __shared__ int sstart[9];
    int tid = threadIdx.x;
    int v0 = blockIdx.x * 8;                          // 6250*8 = NN exact
    if (tid < 9) sstart[tid] = start[v0 + tid];
    __syncthreads();
    int lo = sstart[0], hi = sstart[8];
    int sz = hi - lo;
    bool inl = sz <= ACAP;
    if (inl)
        for (int i = tid; i < sz; i += 512) lp[i] = pairs[lo + i];  // coalesced stage
    __syncthreads();
    const float2* src = inl ? (const float2*)lp : pairs;
    int ofs = inl ? lo : 0;                           // src[j - ofs] == pairs[j]
    int lane = tid & 63;
    int q  = lane >> 3;                // edge slot 0..7
    int fq = lane & 7;                 // feature octet: feats 8fq..8fq+7
    int wid = tid >> 6;
    int v = v0 + wid;
    int a = sstart[wid] - ofs, b = sstart[wid + 1] - ofs;
    v2f a01 = {0.f, 0.f}, a23 = {0.f, 0.f}, a45 = {0.f, 0.f}, a67 = {0.f, 0.f};
    float rs = 0.f;
    int bfull = a + ((b - a) & ~15);
    int j = a;
    float2 pA, pB;
    if (j < bfull) { pA = src[j + q]; pB = src[j + 8 + q]; }       // prologue
    for (; j < bfull; j += 16) {
        uint4 hA = *(const uint4*)(h + (((size_t)__float_as_int(pA.x)) << 6) + 8 * fq);
        uint4 hB = *(const uint4*)(h + (((size_t)__float_as_int(pB.x)) << 6) + 8 * fq);
        int jn = j + 16;
        float2 nA, nB;
        if (jn < bfull) { nA = src[jn + q]; nB = src[jn + 8 + q]; }
        v2f eA = {pA.y, pA.y}, eB = {pB.y, pB.y};
        a01 += eA * bfu2(hA.x);
        a23 += eA * bfu2(hA.y);
        a45 += eA * bfu2(hA.z);
        a67 += eA * bfu2(hA.w);
        a01 += eB * bfu2(hB.x);
        a23 += eB * bfu2(hB.y);
        a45 += eB * bfu2(hB.z);
        a67 += eB * bfu2(hB.w);
        rs += pA.y + pB.y;
        if (jn < bfull) { pA = nA; pB = nB; }
    }
    if (j < b) {                                      // guarded tail, single pass
        int eAi = j + q, eBi = j + 8 + q;
        float2 tA = (eAi < b) ? src[eAi] : make_float2(__int_as_float(0), 0.f);
        float2 tB = (eBi < b) ? src[eBi] : make_float2(__int_as_float(0), 0.f);
        uint4 hA = *(const uint4*)(h + (((size_t)__float_as_int(tA.x)) << 6) + 8 * fq);
        uint4 hB = *(const uint4*)(h + (((size_t)__float_as_int(tB.x)) << 6) + 8 * fq);
        v2f eA = {tA.y, tA.y}, eB = {tB.y, tB.y};
        a01 += eA * bfu2(hA.x);
        a23 += eA * bfu2(hA.y);
        a45 += eA * bfu2(hA.z);
        a67 += eA * bfu2(hA.w);
        a01 += eB * bfu2(hB.x);
        a23 += eB * bfu2(hB.y);
        a45 += eB * bfu2(hB.z);
        a67 += eB * bfu2(hB.w);
        rs += tA.y + tB.y;
    }
#pragma unroll
    for (int off = 8; off <= 32; off <<= 1) {         // reduce across edge slots (q bits)
        v2f t01, t23, t45, t67;
        t01.x = __shfl_xor(a01.x, off, 64); t01.y = __shfl_xor(a01.y, off, 64);
        t23.x = __shfl_xor(a23.x, off, 64); t23.y = __shfl_xor(a23.y, off, 64);
        t45.x = __shfl_xor(a45.x, off, 64); t45.y = __shfl_xor(a45.y, off, 64);
        t67.x = __shfl_xor(a67.x, off, 64); t67.y = __shfl_xor(a67.y, off, 64);
        a01 += t01; a23 += t23; a45 += t45; a67 += t67;
        rs  += __shfl_xor(rs, off, 64);
    }
    // one result per lane: keep feature 8*fq + q (pair q>>1, component q&1)
    v2f ap = (q >> 1) == 0 ? a01 : (q >> 1) == 1 ? a23 : (q >> 1) == 2 ? a45 : a67;
    float av = (q & 1) ? ap.y : ap.x;
    rs += (rs == 0.f) ? 1.f : 0.f;                    // empty-segment fixup (ee>0 otherwise)
    float ev = av / rs;
    ev = ev > 0.f ? ev : expm1f(ev);
    out0[(size_t)v * FOUT + 8 * fq + q] = ev;         // permuted within 256B row
    if (lane == 0) ersum[v] = rs;                     // fixed rowsum, plain store
}

// ---------- K7: out1 = float(edge) AND out2 /= ersum[e0] (fused, runs LAST) ----------
__global__ __launch_bounds__(256) void k_final(const void* __restrict__ edge, const int* __restrict__ iflag,
                                               const float* __restrict__ ersum,
                                               float* __restrict__ out2, float* __restrict__ out1) {
    int i = blockIdx.x * 256 + threadIdx.x;           // 12500*256 = 2*NE exact
    int i64 = *iflag;
    int v = i64 ? (int)((const long long*)edge)[i] : ((const int*)edge)[i];
    out1[i] = (float)v;
    if (i < NE) {                                     // edge[0..NE) is row 0 = e0
        int e0 = v < 0 ? 0 : (v >= NN ? NN - 1 : v);
        out2[i] = out2[i] / ersum[e0];
    }
}

extern "C" void kernel_launch(void* const* d_in, const int* in_sizes, int n_in,
                              void* d_out, int out_size, void* d_ws, size_t ws_size,
                              hipStream_t stream) {
    // Resolve inputs by element count (all distinct).
    int ix[3] = {0, 1, 2}; int nx = 0;
    int iE = 3, iCol = 4, iRowI = 5, iRes = 6, iW = 8, iA1 = 9, iA2 = 10;
    bool a1seen = false;
    for (int i = 0; i < n_in; i++) {
        int s = in_sizes[i];
        if (s == NN * FIN) { if (nx < 3) ix[nx++] = i; }
        else if (s == 2 * NE) iE = i;
        else if (s == 2 * NN) iCol = i;
        else if (s == NN) iRowI = i;
        else if (s == NE) iRes = i;
        else if (s == FIN * FOUT) iW = i;
        else if (s == 2 * FOUT) { if (!a1seen) { iA1 = i; a1seen = true; } else iA2 = i; }
    }
    const float* input = (const float*)d_in[ix[0]];
    const float* p_h   = (const float*)d_in[ix[1]];
    const float* new_h = (const float*)d_in[ix[2]];
    const void* edge       = d_in[iE];
    const void* edge_col   = d_in[iCol];
    const void* row_i      = d_in[iRowI];
    const void* row_resort = d_in[iRes];
    const float* W  = (const float*)d_in[iW];
    const float* a1 = (const float*)d_in[iA1];
    const float* a2 = (const float*)d_in[iA2];

    // Outputs are FLOAT32, concatenated.
    float* out0 = (float*)d_out;                      // N*FOUT
    float* out1 = out0 + (size_t)NN * FOUT;           // 2*NE
    float* out2 = out1 + (size_t)2 * NE;              // NE (edge_e numerator, then in-place divide)

    // Coarse-scatter scratch: out1 region is free until k_final (last kernel).
    uint2* tmp = (uint2*)out1;

    // ws layout (~29 MB; h region reserved as NN*FOUT floats, used as bf16)
    unsigned short* h = (unsigned short*)d_ws;        // NN*FOUT bf16 (6.4 MB used)
    float2* pairs  = (float2*)((float*)d_ws + (size_t)NN * FOUT); // NE float2 (12.8 MB)
    float*  s1     = (float*)(pairs + NE);
    float*  s2     = s1 + NN;
    float*  s4     = s2 + NN;
    float*  ec     = s4 + NN;                         // reused in place as ex
    float*  scf    = ec + NN;                         // float2[NN]: {s3, ecs}
    float*  mseg   = scf + 2 * (size_t)NN;            // zeroed (atomicMax uint bits)
    float*  ssum   = mseg + NN;                       // zeroed
    int*    bcnt   = (int*)(ssum + NN);               // NB
    int*    start  = bcnt + NB;                       // NN+1 (sentinel)
    int*    bstart = start + NN + 1;                  // NB+1
    int*    cntm   = bstart + NB + 1;                 // NBLK*NB (613 KB)
    int*    colpre = cntm + (size_t)NBLK * NB;        // NBLK*NB (613 KB)
    float*  ersum  = (float*)(colpre + (size_t)NBLK * NB);  // NN
    float*  u      = ersum + NN;                      // 512
    int*    iflag  = (int*)(u + 512);

    hipMemsetAsync(mseg, 0, (size_t)2 * NN * sizeof(float), stream);  // mseg, ssum

    k_gemm_su<<<NN / 16 + 2, 256, 0, stream>>>(input, W, h, (const int*)edge, iflag, a1, a2, u);
    k_svec_cnt<<<12500 + NBLK, 256, 0, stream>>>(input, p_h, new_h, u, s1, s2, scf, s4,
                                                 edge, iflag, cntm);
    k_colscore<<<(NN + 255) / 256, 256, 0, stream>>>(s1, s2, edge_col, row_i, iflag, ec, (unsigned int*)mseg);
    k_expsum<<<(NN + 255) / 256, 256, 0, stream>>>(ec, (const unsigned int*)mseg, row_i, iflag, ssum);
    k_norm<<<(NN + 255) / 256, 256, 0, stream>>>(ec, ssum, row_i, iflag, scf);
    k_colscan<<<NB, 1024, 0, stream>>>(cntm, colpre, bcnt);
    k_bscan<<<1, 256, 0, stream>>>(bcnt, bstart, start);
    k_edgeA<<<NBLK, 512, 0, stream>>>((const float2*)scf, s4, edge, row_resort, iflag, bstart, colpre, tmp, out2);
    k_edgeB<<<NB, 512, 0, stream>>>(tmp, bstart, start, pairs);
    k_agg<<<NN / 8, 512, 0, stream>>>(h, pairs, start, ersum, out0);
    k_final<<<2 * NE / 256, 256, 0, stream>>>(edge, iflag, ersum, out2, out1);
}